// Round 2
// baseline (127.297 us; speedup 1.0000x reference)
//
#include <hip/hip_runtime.h>

#define GRIDC 32

__global__ void cd_zero_ws(double* ws) {
    if (threadIdx.x == 0 && blockIdx.x == 0) ws[0] = 0.0;
}

// B=128, NP=32, NS=2048 -> 65536 points/batch, 8388608 total.
// Grid: 8192 blocks = 128 batches x 64 chunks; each block = 1024 contiguous
// points of ONE batch (and ONE primitive: 1024 | 2048). Each thread processes
// exactly one 4-point group -> all loads issue up front, latency hidden by TLP.
__global__ __launch_bounds__(256, 8) void cd_main(
    const float* __restrict__ point, const float* __restrict__ CP,
    const float* __restrict__ tsdfOut, const float* __restrict__ tsdfGT,
    const int* __restrict__ inUse, double* __restrict__ ws)
{
    const int blk  = blockIdx.x;
    const int b    = blk >> 6;        // batch
    const int cblk = blk & 63;        // 1024-point chunk within batch
    const int prim = cblk >> 1;       // primitive (2048 points each)

    // block-uniform scalar load; no branch in the hot path
    const float useF = (inUse[(b << 5) + prim] == 1) ? 1.0f : 0.0f;

    const long long i0 = ((long long)b << 16) + ((long long)cblk << 10)
                       + ((long long)threadIdx.x << 2);   // first point index

    // 4 points = 12 contiguous floats = 3 aligned float4 loads
    const float4* pbase = (const float4*)(point + i0 * 3);
    const float4 pA = pbase[0], pB = pbase[1], pC = pbase[2];
    const float4 to4 = *(const float4*)(tsdfOut + i0);
    const float4 tg4 = *(const float4*)(tsdfGT + i0);

    const float px[4] = {pA.x, pA.w, pB.z, pC.y};
    const float py[4] = {pA.y, pB.x, pB.w, pC.z};
    const float pz[4] = {pA.z, pB.y, pC.x, pC.w};

    const float* cpb = CP + (long long)b * (GRIDC * GRIDC * GRIDC * 3);

    // phase 1: issue all 12 gather loads (unconditional, clamped in-bounds)
    float cx[4], cy[4], cz[4];
    #pragma unroll
    for (int k = 0; k < 4; ++k) {
        // (p + 0.5) * 32, truncate toward zero (matches .astype(int32)), clamp
        int ix = (int)((px[k] + 0.5f) * 32.0f);
        int iy = (int)((py[k] + 0.5f) * 32.0f);
        int iz = (int)((pz[k] + 0.5f) * 32.0f);
        ix = min(max(ix, 0), 31);
        iy = min(max(iy, 0), 31);
        iz = min(max(iz, 0), 31);
        const float* c = cpb + ((ix << 10) + (iy << 5) + iz) * 3;
        cx[k] = c[0]; cy[k] = c[1]; cz[k] = c[2];
    }

    // phase 2: math
    float dsum = 0.0f;
    #pragma unroll
    for (int k = 0; k < 4; ++k) {
        const float dx = px[k] - cx[k];
        const float dy = py[k] - cy[k];
        const float dz = pz[k] - cz[k];
        dsum += sqrtf(dx * dx + dy * dy + dz * dz);
    }
    float lsum = dsum * useF;   // not-in-use -> closest = point -> dist 0

    lsum += fabsf(sqrtf(to4.x) - tg4.x);
    lsum += fabsf(sqrtf(to4.y) - tg4.y);
    lsum += fabsf(sqrtf(to4.z) - tg4.z);
    lsum += fabsf(sqrtf(to4.w) - tg4.w);

    // wave64 reduce -> LDS -> one double atomic per block
    #pragma unroll
    for (int off = 32; off > 0; off >>= 1)
        lsum += __shfl_down(lsum, off, 64);

    __shared__ float wsum[4];
    const int lane = threadIdx.x & 63;
    const int wid  = threadIdx.x >> 6;
    if (lane == 0) wsum[wid] = lsum;
    __syncthreads();
    if (threadIdx.x == 0) {
        const float bsum = wsum[0] + wsum[1] + wsum[2] + wsum[3];
        atomicAdd(ws, (double)bsum);
    }
}

__global__ void cd_finalize(const double* __restrict__ ws, float* __restrict__ out) {
    if (threadIdx.x == 0 && blockIdx.x == 0)
        out[0] = (float)(ws[0] / 8388608.0);
}

extern "C" void kernel_launch(void* const* d_in, const int* in_sizes, int n_in,
                              void* d_out, int out_size, void* d_ws, size_t ws_size,
                              hipStream_t stream) {
    const float* point   = (const float*)d_in[0];
    const float* CP      = (const float*)d_in[1];
    const float* tsdfOut = (const float*)d_in[2];
    const float* tsdfGT  = (const float*)d_in[3];
    const int*   inUse   = (const int*)d_in[4];
    double* ws  = (double*)d_ws;
    float*  out = (float*)d_out;

    hipLaunchKernelGGL(cd_zero_ws, dim3(1), dim3(64), 0, stream, ws);
    hipLaunchKernelGGL(cd_main, dim3(8192), dim3(256), 0, stream,
                       point, CP, tsdfOut, tsdfGT, inUse, ws);
    hipLaunchKernelGGL(cd_finalize, dim3(1), dim3(64), 0, stream, ws, out);
}

// Round 3
// 109.619 us; speedup vs baseline: 1.1613x; 1.1613x over previous
//
#include <hip/hip_runtime.h>

#define GRIDC 32

// B=128, NP=32, NS=2048 -> 65536 points/batch, 8388608 total.
// 4096 blocks x 256 threads; each block = ONE primitive = 2048 contiguous
// points of one batch (uniform inUse). Each thread: 2 groups of 4 points,
// fully unrolled & independent. Per-block partial -> ws[blockIdx] (no atomics).
__global__ __launch_bounds__(256, 8) void cd_main(
    const float* __restrict__ point, const float* __restrict__ CP,
    const float* __restrict__ tsdfOut, const float* __restrict__ tsdfGT,
    const int* __restrict__ inUse, float* __restrict__ partial)
{
    const int blk  = blockIdx.x;
    const int b    = blk >> 5;        // batch (32 blocks per batch)
    const int prim = blk & 31;        // primitive (2048 points each)

    const float useF = (inUse[(b << 5) + prim] == 1) ? 1.0f : 0.0f;

    const long long base = ((long long)blk << 11);  // first point of block

    const float* cpb = CP + (long long)b * (GRIDC * GRIDC * GRIDC * 3);

    float lsum = 0.0f;

    #pragma unroll
    for (int j = 0; j < 2; ++j) {
        const long long i0 = base + (j << 10) + ((long long)threadIdx.x << 2);

        // 4 points = 12 contiguous floats = 3 aligned float4 loads
        const float4* pbase = (const float4*)(point + i0 * 3);
        const float4 pA = pbase[0], pB = pbase[1], pC = pbase[2];
        const float4 to4 = *(const float4*)(tsdfOut + i0);
        const float4 tg4 = *(const float4*)(tsdfGT + i0);

        const float px[4] = {pA.x, pA.w, pB.z, pC.y};
        const float py[4] = {pA.y, pB.x, pB.w, pC.z};
        const float pz[4] = {pA.z, pB.y, pC.x, pC.w};

        float cx[4], cy[4], cz[4];
        #pragma unroll
        for (int k = 0; k < 4; ++k) {
            // (p + 0.5) * 32, truncate toward zero (== .astype(int32)), clamp
            int ix = (int)((px[k] + 0.5f) * 32.0f);
            int iy = (int)((py[k] + 0.5f) * 32.0f);
            int iz = (int)((pz[k] + 0.5f) * 32.0f);
            ix = min(max(ix, 0), 31);
            iy = min(max(iy, 0), 31);
            iz = min(max(iz, 0), 31);
            const float* c = cpb + ((ix << 10) + (iy << 5) + iz) * 3;
            cx[k] = c[0]; cy[k] = c[1]; cz[k] = c[2];
        }

        float dsum = 0.0f;
        #pragma unroll
        for (int k = 0; k < 4; ++k) {
            const float dx = px[k] - cx[k];
            const float dy = py[k] - cy[k];
            const float dz = pz[k] - cz[k];
            dsum += sqrtf(dx * dx + dy * dy + dz * dz);
        }
        lsum += dsum * useF;   // not-in-use -> closest = point -> dist 0

        lsum += fabsf(sqrtf(to4.x) - tg4.x);
        lsum += fabsf(sqrtf(to4.y) - tg4.y);
        lsum += fabsf(sqrtf(to4.z) - tg4.z);
        lsum += fabsf(sqrtf(to4.w) - tg4.w);
    }

    // wave64 reduce -> LDS -> one partial-store per block (no atomics)
    #pragma unroll
    for (int off = 32; off > 0; off >>= 1)
        lsum += __shfl_down(lsum, off, 64);

    __shared__ float wsum[4];
    const int lane = threadIdx.x & 63;
    const int wid  = threadIdx.x >> 6;
    if (lane == 0) wsum[wid] = lsum;
    __syncthreads();
    if (threadIdx.x == 0)
        partial[blk] = wsum[0] + wsum[1] + wsum[2] + wsum[3];
}

// Reduce 4096 float partials -> mean -> out[0]
__global__ __launch_bounds__(256) void cd_finalize(
    const float* __restrict__ partial, float* __restrict__ out)
{
    double d = 0.0;
    #pragma unroll
    for (int j = 0; j < 16; ++j)
        d += (double)partial[threadIdx.x + (j << 8)];

    #pragma unroll
    for (int off = 32; off > 0; off >>= 1)
        d += __shfl_down(d, off, 64);

    __shared__ double wsum[4];
    const int lane = threadIdx.x & 63;
    const int wid  = threadIdx.x >> 6;
    if (lane == 0) wsum[wid] = d;
    __syncthreads();
    if (threadIdx.x == 0)
        out[0] = (float)((wsum[0] + wsum[1] + wsum[2] + wsum[3]) / 8388608.0);
}

extern "C" void kernel_launch(void* const* d_in, const int* in_sizes, int n_in,
                              void* d_out, int out_size, void* d_ws, size_t ws_size,
                              hipStream_t stream) {
    const float* point   = (const float*)d_in[0];
    const float* CP      = (const float*)d_in[1];
    const float* tsdfOut = (const float*)d_in[2];
    const float* tsdfGT  = (const float*)d_in[3];
    const int*   inUse   = (const int*)d_in[4];
    float* partial = (float*)d_ws;     // 4096 floats, fully rewritten each call
    float* out     = (float*)d_out;

    hipLaunchKernelGGL(cd_main, dim3(4096), dim3(256), 0, stream,
                       point, CP, tsdfOut, tsdfGT, inUse, partial);
    hipLaunchKernelGGL(cd_finalize, dim3(1), dim3(256), 0, stream, partial, out);
}

// Round 4
// 58.162 us; speedup vs baseline: 2.1887x; 1.8847x over previous
//
#include <hip/hip_runtime.h>

#define GRIDC 32

// B=128, NP=32, NS=2048 -> 65536 points/batch, 8388608 total.
// 4096 blocks x 256 threads. XCD-aware swizzle: batch b runs only on XCD b&7
// (blockIdx % 8 == XCD round-robin), so each XCD's 4MB L2 holds the ~8
// concurrently-active batches' CP slices (8 x 393KB = 3.1MB) -> gathers hit L2.
// Each block = ONE primitive = 2048 contiguous points (uniform inUse).
// Each thread: 2 independent groups of 4 points. Partial -> ws[blk] (no atomics).
__global__ __launch_bounds__(256, 8) void cd_main(
    const float* __restrict__ point, const float* __restrict__ CP,
    const float* __restrict__ tsdfOut, const float* __restrict__ tsdfGT,
    const int* __restrict__ inUse, float* __restrict__ partial)
{
    const int P    = blockIdx.x;
    const int xcd  = P & 7;
    const int idx  = P >> 3;          // 0..511 within this XCD
    const int b    = ((idx >> 5) << 3) | xcd;   // batch: 16 per XCD, contiguous in time
    const int prim = idx & 31;                  // primitive (2048 points each)

    const float useF = (inUse[(b << 5) + prim] == 1) ? 1.0f : 0.0f;

    const long long base = (((long long)b << 5) | prim) << 11;  // first point

    const float* cpb = CP + (long long)b * (GRIDC * GRIDC * GRIDC * 3);

    float lsum = 0.0f;

    #pragma unroll
    for (int j = 0; j < 2; ++j) {
        const long long i0 = base + (j << 10) + ((long long)threadIdx.x << 2);

        // 4 points = 12 contiguous floats = 3 aligned float4 loads
        const float4* pbase = (const float4*)(point + i0 * 3);
        const float4 pA = pbase[0], pB = pbase[1], pC = pbase[2];
        const float4 to4 = *(const float4*)(tsdfOut + i0);
        const float4 tg4 = *(const float4*)(tsdfGT + i0);

        const float px[4] = {pA.x, pA.w, pB.z, pC.y};
        const float py[4] = {pA.y, pB.x, pB.w, pC.z};
        const float pz[4] = {pA.z, pB.y, pC.x, pC.w};

        float cx[4], cy[4], cz[4];
        #pragma unroll
        for (int k = 0; k < 4; ++k) {
            // (p + 0.5) * 32, truncate toward zero (== .astype(int32)), clamp
            int ix = (int)((px[k] + 0.5f) * 32.0f);
            int iy = (int)((py[k] + 0.5f) * 32.0f);
            int iz = (int)((pz[k] + 0.5f) * 32.0f);
            ix = min(max(ix, 0), 31);
            iy = min(max(iy, 0), 31);
            iz = min(max(iz, 0), 31);
            const float* c = cpb + ((ix << 10) + (iy << 5) + iz) * 3;
            cx[k] = c[0]; cy[k] = c[1]; cz[k] = c[2];
        }

        float dsum = 0.0f;
        #pragma unroll
        for (int k = 0; k < 4; ++k) {
            const float dx = px[k] - cx[k];
            const float dy = py[k] - cy[k];
            const float dz = pz[k] - cz[k];
            dsum += sqrtf(dx * dx + dy * dy + dz * dz);
        }
        lsum += dsum * useF;   // not-in-use -> closest = point -> dist 0

        lsum += fabsf(sqrtf(to4.x) - tg4.x);
        lsum += fabsf(sqrtf(to4.y) - tg4.y);
        lsum += fabsf(sqrtf(to4.z) - tg4.z);
        lsum += fabsf(sqrtf(to4.w) - tg4.w);
    }

    // wave64 reduce -> LDS -> one partial-store per block (no atomics)
    #pragma unroll
    for (int off = 32; off > 0; off >>= 1)
        lsum += __shfl_down(lsum, off, 64);

    __shared__ float wsum[4];
    const int lane = threadIdx.x & 63;
    const int wid  = threadIdx.x >> 6;
    if (lane == 0) wsum[wid] = lsum;
    __syncthreads();
    if (threadIdx.x == 0)
        partial[P] = wsum[0] + wsum[1] + wsum[2] + wsum[3];
}

// Reduce 4096 float partials -> mean -> out[0]
__global__ __launch_bounds__(256) void cd_finalize(
    const float* __restrict__ partial, float* __restrict__ out)
{
    double d = 0.0;
    #pragma unroll
    for (int j = 0; j < 16; ++j)
        d += (double)partial[threadIdx.x + (j << 8)];

    #pragma unroll
    for (int off = 32; off > 0; off >>= 1)
        d += __shfl_down(d, off, 64);

    __shared__ double wsum[4];
    const int lane = threadIdx.x & 63;
    const int wid  = threadIdx.x >> 6;
    if (lane == 0) wsum[wid] = d;
    __syncthreads();
    if (threadIdx.x == 0)
        out[0] = (float)((wsum[0] + wsum[1] + wsum[2] + wsum[3]) / 8388608.0);
}

extern "C" void kernel_launch(void* const* d_in, const int* in_sizes, int n_in,
                              void* d_out, int out_size, void* d_ws, size_t ws_size,
                              hipStream_t stream) {
    const float* point   = (const float*)d_in[0];
    const float* CP      = (const float*)d_in[1];
    const float* tsdfOut = (const float*)d_in[2];
    const float* tsdfGT  = (const float*)d_in[3];
    const int*   inUse   = (const int*)d_in[4];
    float* partial = (float*)d_ws;     // 4096 floats, fully rewritten each call
    float* out     = (float*)d_out;

    hipLaunchKernelGGL(cd_main, dim3(4096), dim3(256), 0, stream,
                       point, CP, tsdfOut, tsdfGT, inUse, partial);
    hipLaunchKernelGGL(cd_finalize, dim3(1), dim3(256), 0, stream, partial, out);
}